// Round 9
// baseline (80.597 us; speedup 1.0000x reference)
//
#include <hip/hip_runtime.h>

// ---------------- problem constants ----------------
#define NROWS    32768
#define KENT     2048
#define OUT_Q_SZ 2097152
#define N_ELEMS  2097152.0f
#define THRG     1e-4f         // cert threshold in g-units (= 2e-4 on d)
#define KLO      0.0009765625f // 1/1024  (g = aA + cA/1024)

typedef _Float16 f16x8  __attribute__((ext_vector_type(8)));
typedef float    f32x16 __attribute__((ext_vector_type(16)));

// ws byte offsets
#define WS_EN    1024      // raw ||e||^2, 2048 f32
#define WS_ENH   9216      // permuted -||e||^2/2 in C-fragment order
#define WS_LIST  20480     // flagged-row list, 32768 u32
#define WS_CBH   262144    // hi f16 fragments (256 KB)
#define WS_CBL   524288    // lo f16 fragments (256 KB)

// ---------------------------------------------------------------------------
// K1: prep — codebook -> f16 hi/lo fragments, norms, zero accumulators.
// ---------------------------------------------------------------------------
__global__ __launch_bounds__(256) void vq_prep_kernel(
    const float* __restrict__ cb, float* __restrict__ ws)
{
    const int unit = blockIdx.x * 256 + threadIdx.x;   // 0..16383
    if (unit == 0) { ws[0] = 0.0f; ((unsigned*)ws)[1] = 0u; ((unsigned*)ws)[2] = 0u; }

    const int gm = unit >> 8, ks = (unit >> 6) & 3, l = unit & 63;
    const int e  = gm * 32 + (l & 31);
    const int ch = ks * 16 + ((l >> 5) << 3);
    float4 v0 = *(const float4*)(cb + e * 64 + ch);
    float4 v1 = *(const float4*)(cb + e * 64 + ch + 4);
    float vv[8] = {v0.x,v0.y,v0.z,v0.w, v1.x,v1.y,v1.z,v1.w};
    f16x8 h, lo;
#pragma unroll
    for (int j = 0; j < 8; ++j) {
        _Float16 hi = (_Float16)vv[j];
        float r = (vv[j] - (float)hi) * 1024.0f;
        h[j] = hi; lo[j] = (_Float16)r;
    }
    *(f16x8*)((_Float16*)((char*)ws + WS_CBH) + (size_t)unit * 8) = h;
    *(f16x8*)((_Float16*)((char*)ws + WS_CBL) + (size_t)unit * 8) = lo;

    if (unit < KENT) {
        const float4* row = (const float4*)(cb + unit * 64);
        float s = 0.0f;
#pragma unroll
        for (int i = 0; i < 16; ++i) {
            float4 v = row[i];
            s += v.x * v.x + v.y * v.y + v.z * v.z + v.w * v.w;
        }
        *((float*)((char*)ws + WS_EN) + unit) = s;
        int ein = unit & 31;
        int half = (ein >> 2) & 1;
        int r = (ein & 3) + ((ein >> 3) << 2);
        *((float*)((char*)ws + WS_ENH) + (unit & ~31) + half * 16 + r) = -0.5f * s;
    }
}

// ---------------------------------------------------------------------------
// K2: main — 512 blocks x 512 threads, 64 rows/block, all 2048 entries.
// 8 waves = 2 row-groups (32 rows each) x 4 entry-quarters.
// Per wave per macro-tile: 12 MFMA (1 hi chain + 1 cross chain), small state
// (~100 VGPR) -> 4 waves/SIMD with grid 512 (2 blocks/CU).
// ---------------------------------------------------------------------------
__global__ __launch_bounds__(512, 4) void vq_main_kernel(
    const float* __restrict__ x, const float* __restrict__ cb,
    float* __restrict__ ws, float* __restrict__ out_q,
    float* __restrict__ out_idx)
{
    __shared__ float lds_x[64 * 68];         // [ch][row0..63], stride 68
    __shared__ float enh_s[2048];
    __shared__ float mb1[64 * 4], mb2[64 * 4];
    __shared__ int   mbi[64 * 4];
    __shared__ int   idx_s[64], flag_s[64];
    __shared__ float wp[8];

    const _Float16* cbh  = (const _Float16*)((char*)ws + WS_CBH);
    const _Float16* cbl  = (const _Float16*)((char*)ws + WS_CBL);
    const float*    enhp = (const float*)((char*)ws + WS_ENH);
    unsigned* cnt  = (unsigned*)ws + 1;
    unsigned* list = (unsigned*)((char*)ws + WS_LIST);

    const int tid = threadIdx.x, bid = blockIdx.x;
    const int n0  = bid * 64;
    const int b   = n0 >> 10;
    const int hw0 = n0 & 1023;
    const float* xg = x + b * 65536 + hw0;

    // ---- stage x tile (64 rows x 64 ch) + enh table ----
    {
        int c = tid >> 3, seg = tid & 7;
        float4 a0 = *(const float4*)(xg + c * 1024 + seg * 8);
        float4 a1 = *(const float4*)(xg + c * 1024 + seg * 8 + 4);
        *(float4*)(&lds_x[c * 68 + seg * 8])     = a0;
        *(float4*)(&lds_x[c * 68 + seg * 8 + 4]) = a1;
    }
#pragma unroll
    for (int i = tid; i < 2048; i += 512) enh_s[i] = enhp[i];
    __syncthreads();

    const int l   = tid & 63;
    const int wv  = tid >> 6;
    const int rgp = wv >> 2;     // rows rgp*32 .. +31
    const int eq  = wv & 3;      // entry quarter (512 entries)
    const int r0  = rgp * 32;

    // B-fragments (hi/lo) for this wave's 32 rows
    f16x8 bh[4], bl[4];
#pragma unroll
    for (int ks = 0; ks < 4; ++ks) {
        f16x8 h, lo;
#pragma unroll
        for (int j = 0; j < 8; ++j) {
            int ch = ks * 16 + ((l >> 5) << 3) + j;
            float f = lds_x[ch * 68 + r0 + (l & 31)];
            _Float16 hi = (_Float16)f;
            float r = (f - (float)hi) * 1024.0f;
            h[j] = hi; lo[j] = (_Float16)r;
        }
        bh[ks] = h; bl[ks] = lo;
    }

    // 4 independent argmax trackers
    float m1[4], m2[4]; int bx[4];
#pragma unroll
    for (int t = 0; t < 4; ++t) { m1[t] = -3.4e38f; m2[t] = -3.4e38f; bx[t] = 0; }

#pragma unroll 2
    for (int m = 0; m < 16; ++m) {
        const int gm = eq * 16 + m;
        const _Float16* ap = cbh + ((size_t)(gm * 4) * 64 + l) * 8;
        const _Float16* lp = cbl + ((size_t)(gm * 4) * 64 + l) * 8;
        f16x8 ah0 = *(const f16x8*)(ap);
        f16x8 ah1 = *(const f16x8*)(ap + 512);
        f16x8 ah2 = *(const f16x8*)(ap + 1024);
        f16x8 ah3 = *(const f16x8*)(ap + 1536);
        f16x8 al0 = *(const f16x8*)(lp);
        f16x8 al1 = *(const f16x8*)(lp + 512);
        f16x8 al2 = *(const f16x8*)(lp + 1024);
        f16x8 al3 = *(const f16x8*)(lp + 1536);

        f32x16 aA;
        {
            const float4* ep4 = (const float4*)(&enh_s[eq * 512 + m * 32 + ((l >> 5) << 4)]);
            float4 q0 = ep4[0], q1 = ep4[1], q2 = ep4[2], q3 = ep4[3];
            aA[0]=q0.x; aA[1]=q0.y; aA[2]=q0.z; aA[3]=q0.w;
            aA[4]=q1.x; aA[5]=q1.y; aA[6]=q1.z; aA[7]=q1.w;
            aA[8]=q2.x; aA[9]=q2.y; aA[10]=q2.z; aA[11]=q2.w;
            aA[12]=q3.x; aA[13]=q3.y; aA[14]=q3.z; aA[15]=q3.w;
        }
        f32x16 cA = {0.f,0.f,0.f,0.f,0.f,0.f,0.f,0.f,0.f,0.f,0.f,0.f,0.f,0.f,0.f,0.f};

        // 12 MFMA: hi chain (4-dep) + cross chain (8-dep)
        aA = __builtin_amdgcn_mfma_f32_32x32x16_f16(ah0, bh[0], aA, 0, 0, 0);
        cA = __builtin_amdgcn_mfma_f32_32x32x16_f16(ah0, bl[0], cA, 0, 0, 0);
        aA = __builtin_amdgcn_mfma_f32_32x32x16_f16(ah1, bh[1], aA, 0, 0, 0);
        cA = __builtin_amdgcn_mfma_f32_32x32x16_f16(ah1, bl[1], cA, 0, 0, 0);
        aA = __builtin_amdgcn_mfma_f32_32x32x16_f16(ah2, bh[2], aA, 0, 0, 0);
        cA = __builtin_amdgcn_mfma_f32_32x32x16_f16(ah2, bl[2], cA, 0, 0, 0);
        aA = __builtin_amdgcn_mfma_f32_32x32x16_f16(ah3, bh[3], aA, 0, 0, 0);
        cA = __builtin_amdgcn_mfma_f32_32x32x16_f16(ah3, bl[3], cA, 0, 0, 0);
        cA = __builtin_amdgcn_mfma_f32_32x32x16_f16(al0, bh[0], cA, 0, 0, 0);
        cA = __builtin_amdgcn_mfma_f32_32x32x16_f16(al1, bh[1], cA, 0, 0, 0);
        cA = __builtin_amdgcn_mfma_f32_32x32x16_f16(al2, bh[2], cA, 0, 0, 0);
        cA = __builtin_amdgcn_mfma_f32_32x32x16_f16(al3, bh[3], cA, 0, 0, 0);

        const int ebl = eq * 512 + m * 32 + ((l >> 5) << 2);
#pragma unroll
        for (int r = 0; r < 16; ++r) {
            int t = r >> 2;
            int ent = ebl + ((r >> 2) << 3) + (r & 3);
            float gA = fmaf(cA[r], KLO, aA[r]);
            bool  tA = gA > m1[t];
            m2[t] = __builtin_amdgcn_fmed3f(gA, m1[t], m2[t]);
            m1[t] = fmaxf(gA, m1[t]);
            bx[t] = tA ? ent : bx[t];
        }
    }

    // ---- merge 4 trackers, then lane-halves; store per-(row, eq) partials
    {
        float v1 = m1[0], v2 = m2[0]; int ix = bx[0];
#pragma unroll
        for (int t = 1; t < 4; ++t) {
            bool gt = (m1[t] > v1) || (m1[t] == v1 && bx[t] < ix);
            float loser = gt ? v1 : m1[t];
            v1 = gt ? m1[t] : v1;
            ix = gt ? bx[t] : ix;
            v2 = fmaxf(loser, fmaxf(v2, m2[t]));
        }
        float o1 = __shfl_xor(v1, 32, 64);
        float o2 = __shfl_xor(v2, 32, 64);
        int   oi = __shfl_xor(ix, 32, 64);
        bool gt = (o1 > v1) || (o1 == v1 && oi < ix);
        float loser = gt ? v1 : o1;
        v1 = gt ? o1 : v1; ix = gt ? oi : ix;
        v2 = fmaxf(loser, fmaxf(v2, o2));
        if (l < 32) {
            int row = r0 + l;
            mb1[row * 4 + eq] = v1;
            mb2[row * 4 + eq] = v2;
            mbi[row * 4 + eq] = ix;
        }
    }
    __syncthreads();

    // ---- final 4-way merge per row; flag near-ties ----
    if (tid < 64) {
        float v1 = -3.4e38f, v2 = -3.4e38f; int ix = 0;
#pragma unroll
        for (int q = 0; q < 4; ++q) {
            float o1 = mb1[tid * 4 + q];
            float o2 = mb2[tid * 4 + q];
            int   oi = mbi[tid * 4 + q];
            bool gt = (o1 > v1) || (o1 == v1 && oi < ix);
            float loser = gt ? v1 : o1;
            v1 = gt ? o1 : v1; ix = gt ? oi : ix;
            v2 = fmaxf(loser, fmaxf(v2, o2));
        }
        out_idx[n0 + tid] = (float)ix;
        int fl = (v1 - v2) <= THRG;
        idx_s[tid] = ix; flag_s[tid] = fl;
        if (fl) { unsigned p = atomicAdd(cnt, 1u); list[p] = n0 + tid; }
    }
    __syncthreads();

    // ---- epilogue: gather, scatter, loss ----
    float lsum = 0.0f;
#pragma unroll
    for (int it = 0; it < 8; ++it) {
        int e = it * 512 + tid;     // 0..4095
        int c = e >> 6, r = e & 63;
        float q  = cb[idx_s[r] * 64 + c];
        float xv = lds_x[c * 68 + r];
        out_q[(b << 16) + (c << 10) + hw0 + r] = xv + (q - xv);
        float df = q - xv;
        lsum += flag_s[r] ? 0.0f : df * df;
    }
#pragma unroll
    for (int mm = 1; mm < 64; mm <<= 1) lsum += __shfl_xor(lsum, mm, 64);
    if (l == 0) wp[wv] = lsum;
    __syncthreads();
    if (tid == 0) {
        float s = 0.0f;
#pragma unroll
        for (int w = 0; w < 8; ++w) s += wp[w];
        atomicAdd(ws, s);
    }
}

// ---------------------------------------------------------------------------
// K3: exact fp32 re-scan for flagged rows; last block writes scalar losses.
// ---------------------------------------------------------------------------
__global__ __launch_bounds__(256) void vq_fallback_kernel(
    const float* __restrict__ x, const float* __restrict__ cb,
    float* __restrict__ ws, float* __restrict__ out_q, float* __restrict__ out_idx)
{
    __shared__ float x_s[64];
    __shared__ float rd[256];
    __shared__ int   ri[256];
    __shared__ unsigned lastflag;

    const float* en = (const float*)((char*)ws + WS_EN);
    const unsigned F = *(const unsigned*)((char*)ws + 4);
    const unsigned* list = (const unsigned*)((char*)ws + WS_LIST);
    unsigned* done = (unsigned*)ws + 2;
    const int t = threadIdx.x;

    for (unsigned li = blockIdx.x; li < F; li += gridDim.x) {
        int row = list[li];
        int b = row >> 10, hw = row & 1023;
        if (t < 64) x_s[t] = x[(b << 16) + (t << 10) + hw];
        __syncthreads();

        float best = 3.4e38f; int bi = 0;
#pragma unroll 1
        for (int i = 0; i < 8; ++i) {
            int e = i * 256 + t;
            float dot = 0.0f;
#pragma unroll
            for (int c4 = 0; c4 < 16; ++c4) {
                float4 cv = *(const float4*)(cb + e * 64 + c4 * 4);
                float4 xv = *(const float4*)&x_s[c4 * 4];
                dot += cv.x * xv.x + cv.y * xv.y + cv.z * xv.z + cv.w * xv.w;
            }
            float d = en[e] - 2.0f * dot;
            if (d < best) { best = d; bi = e; }
        }
        rd[t] = best; ri[t] = bi;
        __syncthreads();
        for (int s = 128; s > 0; s >>= 1) {
            if (t < s) {
                bool lt = (rd[t + s] < rd[t]) ||
                          (rd[t + s] == rd[t] && ri[t + s] < ri[t]);
                if (lt) { rd[t] = rd[t + s]; ri[t] = ri[t + s]; }
            }
            __syncthreads();
        }
        int ix = ri[0];
        if (t == 0) out_idx[row] = (float)ix;
        if (t < 64) {
            float q = cb[ix * 64 + t];
            float xv = x_s[t];
            out_q[(b << 16) + (t << 10) + hw] = xv + (q - xv);
            float df = q - xv;
            float ls = df * df;
#pragma unroll
            for (int mm = 1; mm < 64; mm <<= 1) ls += __shfl_xor(ls, mm, 64);
            if (t == 0) atomicAdd(ws, ls);
        }
        __syncthreads();
    }

    // ---- last-block finalize ----
    __threadfence();
    if (t == 0) lastflag = atomicAdd(done, 1u);
    __syncthreads();
    if (lastflag == gridDim.x - 1 && t == 0) {
        float m = (*(volatile float*)ws) * (1.0f / N_ELEMS);
        out_q[OUT_Q_SZ]     = m;   // codebook_loss
        out_q[OUT_Q_SZ + 1] = m;   // commitment_loss
    }
}

extern "C" void kernel_launch(void* const* d_in, const int* in_sizes, int n_in,
                              void* d_out, int out_size, void* d_ws, size_t ws_size,
                              hipStream_t stream) {
    const float* x  = (const float*)d_in[0];   // (32,64,32,32)
    const float* cb = (const float*)d_in[1];   // (2048,64)
    float* out  = (float*)d_out;
    float* ws   = (float*)d_ws;
    float* oidx = out + OUT_Q_SZ + 2;

    vq_prep_kernel<<<64, 256, 0, stream>>>(cb, ws);
    vq_main_kernel<<<512, 512, 0, stream>>>(x, cb, ws, out, oidx);
    vq_fallback_kernel<<<64, 256, 0, stream>>>(x, cb, ws, out, oidx);
}

// Round 10
// 71.941 us; speedup vs baseline: 1.1203x; 1.1203x over previous
//
#include <hip/hip_runtime.h>

// ---------------- problem constants ----------------
#define NROWS    32768
#define KENT     2048
#define OUT_Q_SZ 2097152
#define N_ELEMS  2097152.0f
#define THRG     1e-4f         // cert threshold in g-units (= 2e-4 on d)
#define KLO      0.0009765625f // 1/1024  (g = aA + cA/1024)

typedef _Float16 f16x8  __attribute__((ext_vector_type(8)));
typedef float    f32x16 __attribute__((ext_vector_type(16)));

// ws byte offsets
#define WS_EN    1024      // raw ||e||^2, 2048 f32
#define WS_ENH   9216      // permuted -||e||^2/2 in C-fragment order
#define WS_LIST  20480     // flagged-row list, 32768 u32
#define WS_CBH   262144    // hi f16 fragments (256 KB)
#define WS_CBL   524288    // lo f16 fragments (256 KB)

// ---------------------------------------------------------------------------
// K1: prep — codebook -> f16 hi/lo fragments, norms, zero accumulators.
// ---------------------------------------------------------------------------
__global__ __launch_bounds__(256) void vq_prep_kernel(
    const float* __restrict__ cb, float* __restrict__ ws)
{
    const int unit = blockIdx.x * 256 + threadIdx.x;   // 0..16383
    if (unit == 0) { ws[0] = 0.0f; ((unsigned*)ws)[1] = 0u; ((unsigned*)ws)[2] = 0u; }

    const int gm = unit >> 8, ks = (unit >> 6) & 3, l = unit & 63;
    const int e  = gm * 32 + (l & 31);
    const int ch = ks * 16 + ((l >> 5) << 3);
    float4 v0 = *(const float4*)(cb + e * 64 + ch);
    float4 v1 = *(const float4*)(cb + e * 64 + ch + 4);
    float vv[8] = {v0.x,v0.y,v0.z,v0.w, v1.x,v1.y,v1.z,v1.w};
    f16x8 h, lo;
#pragma unroll
    for (int j = 0; j < 8; ++j) {
        _Float16 hi = (_Float16)vv[j];
        float r = (vv[j] - (float)hi) * 1024.0f;
        h[j] = hi; lo[j] = (_Float16)r;
    }
    *(f16x8*)((_Float16*)((char*)ws + WS_CBH) + (size_t)unit * 8) = h;
    *(f16x8*)((_Float16*)((char*)ws + WS_CBL) + (size_t)unit * 8) = lo;

    if (unit < KENT) {
        const float4* row = (const float4*)(cb + unit * 64);
        float s = 0.0f;
#pragma unroll
        for (int i = 0; i < 16; ++i) {
            float4 v = row[i];
            s += v.x * v.x + v.y * v.y + v.z * v.z + v.w * v.w;
        }
        *((float*)((char*)ws + WS_EN) + unit) = s;
        int ein = unit & 31;
        int half = (ein >> 2) & 1;
        int r = (ein & 3) + ((ein >> 3) << 2);
        *((float*)((char*)ws + WS_ENH) + (unit & ~31) + half * 16 + r) = -0.5f * s;
    }
}

// ---------------------------------------------------------------------------
// K2: main — 512 blocks x 512 threads, 64 rows/block, all 2048 entries.
// 8 waves; EVERY wave covers all 64 rows (2 B-sets) x its entry-EIGHTH
// (256 entries = 8 macro-tiles). 24 MFMA per 8 A-loads (R6 reuse ratio),
// grid 512 = 2 blocks/CU = 4 waves/SIMD (launch_bounds(512,2) -> cap 128).
// ---------------------------------------------------------------------------
__global__ __launch_bounds__(512, 2) void vq_main_kernel(
    const float* __restrict__ x, const float* __restrict__ cb,
    float* __restrict__ ws, float* __restrict__ out_q,
    float* __restrict__ out_idx)
{
    __shared__ float lds_x[64 * 68];         // [ch][row0..63], stride 68
    __shared__ float enh_s[2048];
    __shared__ float mb1[64 * 8], mb2[64 * 8];
    __shared__ int   mbi[64 * 8];
    __shared__ int   idx_s[64], flag_s[64];
    __shared__ float wp[8];

    const _Float16* cbh  = (const _Float16*)((char*)ws + WS_CBH);
    const _Float16* cbl  = (const _Float16*)((char*)ws + WS_CBL);
    const float*    enhp = (const float*)((char*)ws + WS_ENH);
    unsigned* cnt  = (unsigned*)ws + 1;
    unsigned* list = (unsigned*)((char*)ws + WS_LIST);

    const int tid = threadIdx.x, bid = blockIdx.x;
    const int n0  = bid * 64;
    const int b   = n0 >> 10;
    const int hw0 = n0 & 1023;
    const float* xg = x + b * 65536 + hw0;

    // ---- stage x tile (64 rows x 64 ch) + enh table ----
    {
        int c = tid >> 3, seg = tid & 7;
        float4 a0 = *(const float4*)(xg + c * 1024 + seg * 8);
        float4 a1 = *(const float4*)(xg + c * 1024 + seg * 8 + 4);
        *(float4*)(&lds_x[c * 68 + seg * 8])     = a0;
        *(float4*)(&lds_x[c * 68 + seg * 8 + 4]) = a1;
    }
#pragma unroll
    for (int i = tid; i < 2048; i += 512) enh_s[i] = enhp[i];
    __syncthreads();

    const int l  = tid & 63;
    const int eq = tid >> 6;     // entry eighth (256 entries), wave id

    // B-fragments (hi/lo) for two 32-row sub-tiles (all 64 rows of block)
    f16x8 bh[2][4], bl[2][4];
#pragma unroll
    for (int s = 0; s < 2; ++s)
#pragma unroll
        for (int ks = 0; ks < 4; ++ks) {
            f16x8 h, lo;
#pragma unroll
            for (int j = 0; j < 8; ++j) {
                int ch = ks * 16 + ((l >> 5) << 3) + j;
                float f = lds_x[ch * 68 + s * 32 + (l & 31)];
                _Float16 hi = (_Float16)f;
                float r = (f - (float)hi) * 1024.0f;
                h[j] = hi; lo[j] = (_Float16)r;
            }
            bh[s][ks] = h; bl[s][ks] = lo;
        }

    // 4 independent argmax trackers per B-set
    float m1[2][4], m2[2][4]; int bx[2][4];
#pragma unroll
    for (int s = 0; s < 2; ++s)
#pragma unroll
        for (int t = 0; t < 4; ++t) { m1[s][t] = -3.4e38f; m2[s][t] = -3.4e38f; bx[s][t] = 0; }

#pragma unroll 2
    for (int m = 0; m < 8; ++m) {
        const int gm = eq * 8 + m;
        const _Float16* ap = cbh + ((size_t)(gm * 4) * 64 + l) * 8;
        const _Float16* lp = cbl + ((size_t)(gm * 4) * 64 + l) * 8;
        f16x8 ah0 = *(const f16x8*)(ap);
        f16x8 ah1 = *(const f16x8*)(ap + 512);
        f16x8 ah2 = *(const f16x8*)(ap + 1024);
        f16x8 ah3 = *(const f16x8*)(ap + 1536);
        f16x8 al0 = *(const f16x8*)(lp);
        f16x8 al1 = *(const f16x8*)(lp + 512);
        f16x8 al2 = *(const f16x8*)(lp + 1024);
        f16x8 al3 = *(const f16x8*)(lp + 1536);

        f32x16 aA;
        {
            const float4* ep4 = (const float4*)(&enh_s[eq * 256 + m * 32 + ((l >> 5) << 4)]);
            float4 q0 = ep4[0], q1 = ep4[1], q2 = ep4[2], q3 = ep4[3];
            aA[0]=q0.x; aA[1]=q0.y; aA[2]=q0.z; aA[3]=q0.w;
            aA[4]=q1.x; aA[5]=q1.y; aA[6]=q1.z; aA[7]=q1.w;
            aA[8]=q2.x; aA[9]=q2.y; aA[10]=q2.z; aA[11]=q2.w;
            aA[12]=q3.x; aA[13]=q3.y; aA[14]=q3.z; aA[15]=q3.w;
        }
        f32x16 aB = aA;
        f32x16 cA = {0.f,0.f,0.f,0.f,0.f,0.f,0.f,0.f,0.f,0.f,0.f,0.f,0.f,0.f,0.f,0.f};
        f32x16 cB = cA;

        // 24 MFMA, 4 independent chains
        aA = __builtin_amdgcn_mfma_f32_32x32x16_f16(ah0, bh[0][0], aA, 0, 0, 0);
        aB = __builtin_amdgcn_mfma_f32_32x32x16_f16(ah0, bh[1][0], aB, 0, 0, 0);
        cA = __builtin_amdgcn_mfma_f32_32x32x16_f16(ah0, bl[0][0], cA, 0, 0, 0);
        cB = __builtin_amdgcn_mfma_f32_32x32x16_f16(ah0, bl[1][0], cB, 0, 0, 0);
        aA = __builtin_amdgcn_mfma_f32_32x32x16_f16(ah1, bh[0][1], aA, 0, 0, 0);
        aB = __builtin_amdgcn_mfma_f32_32x32x16_f16(ah1, bh[1][1], aB, 0, 0, 0);
        cA = __builtin_amdgcn_mfma_f32_32x32x16_f16(ah1, bl[0][1], cA, 0, 0, 0);
        cB = __builtin_amdgcn_mfma_f32_32x32x16_f16(ah1, bl[1][1], cB, 0, 0, 0);
        aA = __builtin_amdgcn_mfma_f32_32x32x16_f16(ah2, bh[0][2], aA, 0, 0, 0);
        aB = __builtin_amdgcn_mfma_f32_32x32x16_f16(ah2, bh[1][2], aB, 0, 0, 0);
        cA = __builtin_amdgcn_mfma_f32_32x32x16_f16(ah2, bl[0][2], cA, 0, 0, 0);
        cB = __builtin_amdgcn_mfma_f32_32x32x16_f16(ah2, bl[1][2], cB, 0, 0, 0);
        aA = __builtin_amdgcn_mfma_f32_32x32x16_f16(ah3, bh[0][3], aA, 0, 0, 0);
        aB = __builtin_amdgcn_mfma_f32_32x32x16_f16(ah3, bh[1][3], aB, 0, 0, 0);
        cA = __builtin_amdgcn_mfma_f32_32x32x16_f16(ah3, bl[0][3], cA, 0, 0, 0);
        cB = __builtin_amdgcn_mfma_f32_32x32x16_f16(ah3, bl[1][3], cB, 0, 0, 0);
        cA = __builtin_amdgcn_mfma_f32_32x32x16_f16(al0, bh[0][0], cA, 0, 0, 0);
        cB = __builtin_amdgcn_mfma_f32_32x32x16_f16(al0, bh[1][0], cB, 0, 0, 0);
        cA = __builtin_amdgcn_mfma_f32_32x32x16_f16(al1, bh[0][1], cA, 0, 0, 0);
        cB = __builtin_amdgcn_mfma_f32_32x32x16_f16(al1, bh[1][1], cB, 0, 0, 0);
        cA = __builtin_amdgcn_mfma_f32_32x32x16_f16(al2, bh[0][2], cA, 0, 0, 0);
        cB = __builtin_amdgcn_mfma_f32_32x32x16_f16(al2, bh[1][2], cB, 0, 0, 0);
        cA = __builtin_amdgcn_mfma_f32_32x32x16_f16(al3, bh[0][3], cA, 0, 0, 0);
        cB = __builtin_amdgcn_mfma_f32_32x32x16_f16(al3, bh[1][3], cB, 0, 0, 0);

        const int ebl = eq * 256 + m * 32 + ((l >> 5) << 2);
#pragma unroll
        for (int r = 0; r < 16; ++r) {
            int t = r >> 2;
            int ent = ebl + ((r >> 2) << 3) + (r & 3);
            float gA = fmaf(cA[r], KLO, aA[r]);
            bool  tA = gA > m1[0][t];
            m2[0][t] = __builtin_amdgcn_fmed3f(gA, m1[0][t], m2[0][t]);
            m1[0][t] = fmaxf(gA, m1[0][t]);
            bx[0][t] = tA ? ent : bx[0][t];
            float gB = fmaf(cB[r], KLO, aB[r]);
            bool  tB = gB > m1[1][t];
            m2[1][t] = __builtin_amdgcn_fmed3f(gB, m1[1][t], m2[1][t]);
            m1[1][t] = fmaxf(gB, m1[1][t]);
            bx[1][t] = tB ? ent : bx[1][t];
        }
    }

    // ---- merge trackers + lane-halves; store per-(row, eq) partials ----
#pragma unroll
    for (int s = 0; s < 2; ++s) {
        float v1 = m1[s][0], v2 = m2[s][0]; int ix = bx[s][0];
#pragma unroll
        for (int t = 1; t < 4; ++t) {
            bool gt = (m1[s][t] > v1) || (m1[s][t] == v1 && bx[s][t] < ix);
            float loser = gt ? v1 : m1[s][t];
            v1 = gt ? m1[s][t] : v1;
            ix = gt ? bx[s][t] : ix;
            v2 = fmaxf(loser, fmaxf(v2, m2[s][t]));
        }
        float o1 = __shfl_xor(v1, 32, 64);
        float o2 = __shfl_xor(v2, 32, 64);
        int   oi = __shfl_xor(ix, 32, 64);
        bool gt = (o1 > v1) || (o1 == v1 && oi < ix);
        float loser = gt ? v1 : o1;
        v1 = gt ? o1 : v1; ix = gt ? oi : ix;
        v2 = fmaxf(loser, fmaxf(v2, o2));
        if (l < 32) {
            int row = s * 32 + l;
            mb1[row * 8 + eq] = v1;
            mb2[row * 8 + eq] = v2;
            mbi[row * 8 + eq] = ix;
        }
    }
    __syncthreads();

    // ---- final 8-way merge per row; flag near-ties ----
    if (tid < 64) {
        float v1 = -3.4e38f, v2 = -3.4e38f; int ix = 0;
#pragma unroll
        for (int q = 0; q < 8; ++q) {
            float o1 = mb1[tid * 8 + q];
            float o2 = mb2[tid * 8 + q];
            int   oi = mbi[tid * 8 + q];
            bool gt = (o1 > v1) || (o1 == v1 && oi < ix);
            float loser = gt ? v1 : o1;
            v1 = gt ? o1 : v1; ix = gt ? oi : ix;
            v2 = fmaxf(loser, fmaxf(v2, o2));
        }
        out_idx[n0 + tid] = (float)ix;
        int fl = (v1 - v2) <= THRG;
        idx_s[tid] = ix; flag_s[tid] = fl;
        if (fl) { unsigned p = atomicAdd(cnt, 1u); list[p] = n0 + tid; }
    }
    __syncthreads();

    // ---- epilogue: gather, scatter, loss ----
    float lsum = 0.0f;
#pragma unroll
    for (int it = 0; it < 8; ++it) {
        int e = it * 512 + tid;     // 0..4095
        int c = e >> 6, r = e & 63;
        float q  = cb[idx_s[r] * 64 + c];
        float xv = lds_x[c * 68 + r];
        out_q[(b << 16) + (c << 10) + hw0 + r] = xv + (q - xv);
        float df = q - xv;
        lsum += flag_s[r] ? 0.0f : df * df;
    }
#pragma unroll
    for (int mm = 1; mm < 64; mm <<= 1) lsum += __shfl_xor(lsum, mm, 64);
    if (l == 0) wp[eq] = lsum;
    __syncthreads();
    if (tid == 0) {
        float s = 0.0f;
#pragma unroll
        for (int w = 0; w < 8; ++w) s += wp[w];
        atomicAdd(ws, s);
    }
}

// ---------------------------------------------------------------------------
// K3: exact fp32 re-scan for flagged rows; last block writes scalar losses.
// ---------------------------------------------------------------------------
__global__ __launch_bounds__(256) void vq_fallback_kernel(
    const float* __restrict__ x, const float* __restrict__ cb,
    float* __restrict__ ws, float* __restrict__ out_q, float* __restrict__ out_idx)
{
    __shared__ float x_s[64];
    __shared__ float rd[256];
    __shared__ int   ri[256];
    __shared__ unsigned lastflag;

    const float* en = (const float*)((char*)ws + WS_EN);
    const unsigned F = *(const unsigned*)((char*)ws + 4);
    const unsigned* list = (const unsigned*)((char*)ws + WS_LIST);
    unsigned* done = (unsigned*)ws + 2;
    const int t = threadIdx.x;

    for (unsigned li = blockIdx.x; li < F; li += gridDim.x) {
        int row = list[li];
        int b = row >> 10, hw = row & 1023;
        if (t < 64) x_s[t] = x[(b << 16) + (t << 10) + hw];
        __syncthreads();

        float best = 3.4e38f; int bi = 0;
#pragma unroll 1
        for (int i = 0; i < 8; ++i) {
            int e = i * 256 + t;
            float dot = 0.0f;
#pragma unroll
            for (int c4 = 0; c4 < 16; ++c4) {
                float4 cv = *(const float4*)(cb + e * 64 + c4 * 4);
                float4 xv = *(const float4*)&x_s[c4 * 4];
                dot += cv.x * xv.x + cv.y * xv.y + cv.z * xv.z + cv.w * xv.w;
            }
            float d = en[e] - 2.0f * dot;
            if (d < best) { best = d; bi = e; }
        }
        rd[t] = best; ri[t] = bi;
        __syncthreads();
        for (int s = 128; s > 0; s >>= 1) {
            if (t < s) {
                bool lt = (rd[t + s] < rd[t]) ||
                          (rd[t + s] == rd[t] && ri[t + s] < ri[t]);
                if (lt) { rd[t] = rd[t + s]; ri[t] = ri[t + s]; }
            }
            __syncthreads();
        }
        int ix = ri[0];
        if (t == 0) out_idx[row] = (float)ix;
        if (t < 64) {
            float q = cb[ix * 64 + t];
            float xv = x_s[t];
            out_q[(b << 16) + (t << 10) + hw] = xv + (q - xv);
            float df = q - xv;
            float ls = df * df;
#pragma unroll
            for (int mm = 1; mm < 64; mm <<= 1) ls += __shfl_xor(ls, mm, 64);
            if (t == 0) atomicAdd(ws, ls);
        }
        __syncthreads();
    }

    // ---- last-block finalize ----
    __threadfence();
    if (t == 0) lastflag = atomicAdd(done, 1u);
    __syncthreads();
    if (lastflag == gridDim.x - 1 && t == 0) {
        float m = (*(volatile float*)ws) * (1.0f / N_ELEMS);
        out_q[OUT_Q_SZ]     = m;   // codebook_loss
        out_q[OUT_Q_SZ + 1] = m;   // commitment_loss
    }
}

extern "C" void kernel_launch(void* const* d_in, const int* in_sizes, int n_in,
                              void* d_out, int out_size, void* d_ws, size_t ws_size,
                              hipStream_t stream) {
    const float* x  = (const float*)d_in[0];   // (32,64,32,32)
    const float* cb = (const float*)d_in[1];   // (2048,64)
    float* out  = (float*)d_out;
    float* ws   = (float*)d_ws;
    float* oidx = out + OUT_Q_SZ + 2;

    vq_prep_kernel<<<64, 256, 0, stream>>>(cb, ws);
    vq_main_kernel<<<512, 512, 0, stream>>>(x, cb, ws, out, oidx);
    vq_fallback_kernel<<<64, 256, 0, stream>>>(x, cb, ws, out, oidx);
}